// Round 4
// baseline (229.744 us; speedup 1.0000x reference)
//
#include <hip/hip_runtime.h>
#include <stdint.h>

// DyDCNv2 + GroupNorm(16). B=8, C=O=256, H=W=64, fp32 in/out.
// Implicit GEMM M=32768,N=256,K=2304 bf16 MFMA.
// R4: 32-pos tiles grid=1024 (4 blocks/CU, 16 waves/CU), gather prefetch
// distance 2, LDS-only barrier (keeps global loads in flight across s_barrier),
// 32-ch K-steps to fit 128 VGPR.

#define B_ 8
#define C_ 256
#define O_ 256
#define H_ 64
#define W_ 64
#define HW_ 4096
#define KTOT 2304
#define GROUPS_ 16
#define EPS_ 1e-5f
#define NSTEP 72           // 72 steps x 32 ch
#define VROW 40            // lds_v row stride in u16 (32 data + 8 pad)

typedef float  f32x4  __attribute__((ext_vector_type(4)));
typedef short  short8 __attribute__((ext_vector_type(8)));
typedef unsigned int   u32;
typedef unsigned short u16;

// workspace layout (bytes)
#define XT_BYTES (B_*HW_*C_*2)                 // 16,777,216  xt [B][HW][C] bf16
#define WIMG_OFF  XT_BYTES
#define WIMG_BYTES (72*16*64*16)               // 1,179,648  frag-packed bf16 weights
#define STATS_OFF (WIMG_OFF + WIMG_BYTES)      // 256 floats

__device__ __forceinline__ u32 bf16r(float f) {  // RNE f32->bf16
    u32 u = __float_as_uint(f);
    return (u + 0x7fffu + ((u >> 16) & 1u)) >> 16;
}
__device__ __forceinline__ u32 pack_bf16x2(float lo, float hi) {
    return bf16r(lo) | (bf16r(hi) << 16);
}
__device__ __forceinline__ float bflo(u32 u) { return __uint_as_float(u << 16); }
__device__ __forceinline__ float bfhi(u32 u) { return __uint_as_float(u & 0xffff0000u); }

// barrier that waits only on LDS ops: global (register-destined) loads stay in flight
__device__ __forceinline__ void barrier_lds() {
    asm volatile("s_waitcnt lgkmcnt(0)\n\ts_barrier" ::: "memory");
}

// ---------------------------------------------------------------- prep: transpose + packw fused
__global__ void k_prep(const float* __restrict__ x, u16* __restrict__ xt,
                       const float* __restrict__ w, u16* __restrict__ wimg) {
    __shared__ float tile[32][33];
    const int bid = blockIdx.x;
    const int tid = threadIdx.x;
    if (bid < 8192) {
        // transpose x[B][C][HW] -> xt[B][HW][C] bf16
        const int pt = bid & 127, ct = (bid >> 7) & 7, b = bid >> 10;
        const int tx = tid & 31, ty = tid >> 5;
        const int p = pt * 32 + tx;
#pragma unroll
        for (int i = 0; i < 4; ++i) {
            int c = ct * 32 + ty + i * 8;
            tile[ty + i * 8][tx] = x[(((size_t)b * C_ + c) << 12) + p];
        }
        __syncthreads();
        const int cp = tx & 15;
        const int ps = ty + (tx >> 4) * 8;
#pragma unroll
        for (int i = 0; i < 2; ++i) {
            const int pl = ps + i * 16;
            u32 v = pack_bf16x2(tile[2 * cp][pl], tile[2 * cp + 1][pl]);
            *(u32*)&xt[((((size_t)b << 12) + pt * 32 + pl) << 8) + ct * 32 + 2 * cp] = v;
        }
    } else {
        // pack weights: wimg[sub][frag][lane][8], sub = k*8+ctile;
        // lane(col,quad) holds W[n=frag*16+col][c0+quad*8+j][k]
        const int sub = bid - 8192;       // 0..71
        const int k  = sub >> 3;
        const int c0 = (sub & 7) * 32;
#pragma unroll
        for (int i = 0; i < 4; ++i) {
            const int item = tid + i * 256;    // frag*64 + lane
            const int lane = item & 63;
            const int frag = item >> 6;
            const int col = lane & 15, quad = lane >> 4;
            const int n = frag * 16 + col;
            const float* src = w + (size_t)n * KTOT + (size_t)(c0 + quad * 8) * 9 + k;
            u32 o[4];
#pragma unroll
            for (int j = 0; j < 4; ++j)
                o[j] = pack_bf16x2(src[(size_t)(2 * j) * 9], src[(size_t)(2 * j + 1) * 9]);
            *(uint4*)&wimg[((size_t)sub * 1024 + item) * 8] = *(uint4*)o;
        }
    }
}

// ---------------------------------------------------------------- k_dcn helpers
// gather 4 ch (uint2) per corner; meta_i holds pre-scaled row offsets (row*256)
__device__ __forceinline__ void issue_gather(const u16* __restrict__ cb,
                                             const float* __restrict__ mwp,
                                             const int* __restrict__ mip,
                                             int gpos, uint2 g[4], f32x4& mw) {
    mw = *(const f32x4*)&mwp[gpos * 4];
    const int4 ix = *(const int4*)&mip[gpos * 4];
    g[0] = *(const uint2*)(cb + ix.x);
    g[1] = *(const uint2*)(cb + ix.y);
    g[2] = *(const uint2*)(cb + ix.z);
    g[3] = *(const uint2*)(cb + ix.w);
}

__device__ __forceinline__ void interp_store(const uint2 g[4], f32x4 mw, u16* dst) {
    f32x4 a = (f32x4){0.f, 0.f, 0.f, 0.f};
    const float ww[4] = {mw.x, mw.y, mw.z, mw.w};
#pragma unroll
    for (int cr = 0; cr < 4; ++cr) {
        const float wg = ww[cr];
        a.x += wg * bflo(g[cr].x);
        a.y += wg * bfhi(g[cr].x);
        a.z += wg * bflo(g[cr].y);
        a.w += wg * bfhi(g[cr].y);
    }
    uint2 pk;
    pk.x = pack_bf16x2(a.x, a.y);
    pk.y = pack_bf16x2(a.z, a.w);
    *(uint2*)dst = pk;
}

// ---------------------------------------------------------------- main fused DCN GEMM
// 1-D grid 1024: b = gid%8 (XCD-affine), m-tile 32 pos = gid/8. 256 thr = 4 waves;
// wave w: 32 pos x n in [w*64, w*64+64). Step = 32 channels.
__launch_bounds__(256, 4)
__global__ void k_dcn(const u16* __restrict__ xt, const u16* __restrict__ wimg,
                      const float* __restrict__ offp, const float* __restrict__ mskp,
                      float* __restrict__ out, float* __restrict__ stats) {
    __shared__ __align__(16) float meta_w[9 * 32 * 4];   // 4608 B
    __shared__ __align__(16) int   meta_i[9 * 32 * 4];   // 4608 B
    __shared__ __align__(16) u16   lds_v[2][32 * VROW];  // 5120 B dbuf val tile

    const int tid = threadIdx.x;
    const int gid = blockIdx.x;
    const int b   = gid & 7;            // XCD-affine
    const int m0  = (gid >> 3) * 32;
    const int lane = tid & 63, wid = tid >> 6;
    const int col = lane & 15, quad = lane >> 4;
    const int gpos = tid >> 3, oct = tid & 7;   // gather role: (pos 0..31, 4-ch octet 0..7)

    const u16* xtb = xt + ((size_t)b << 20);

    // ---- bilinear meta for 32 positions x 9 kernel points, once
    for (int it = tid; it < 288; it += 256) {
        const int pos = it & 31, k = it >> 5;
        const int pg = m0 + pos;
        const int hh = pg >> 6, wwi = pg & 63;
        const float dy = offp[((size_t)(b * 18 + 2 * k) << 12) + pg];
        const float dx = offp[((size_t)(b * 18 + 2 * k + 1) << 12) + pg];
        const float mv = mskp[((size_t)(b * 9 + k) << 12) + pg];
        const float ys = (float)(hh + (k / 3) - 1) + dy;
        const float xs = (float)(wwi + (k % 3) - 1) + dx;
        const float y0f = floorf(ys), x0f = floorf(xs);
        const int y0 = (int)y0f, x0 = (int)x0f;
        const float wy1 = ys - y0f, wx1 = xs - x0f;
        const float wy0 = 1.f - wy1, wx0 = 1.f - wx1;
        const int y1 = y0 + 1, x1 = x0 + 1;
        const float vy0 = (y0 >= 0 && y0 < H_) ? 1.f : 0.f;
        const float vy1 = (y1 >= 0 && y1 < H_) ? 1.f : 0.f;
        const float vx0 = (x0 >= 0 && x0 < W_) ? 1.f : 0.f;
        const float vx1 = (x1 >= 0 && x1 < W_) ? 1.f : 0.f;
        const int y0c = min(max(y0, 0), H_ - 1), y1c = min(max(y1, 0), H_ - 1);
        const int x0c = min(max(x0, 0), W_ - 1), x1c = min(max(x1, 0), W_ - 1);
        meta_w[it * 4 + 0] = mv * wy0 * wx0 * vy0 * vx0;
        meta_w[it * 4 + 1] = mv * wy0 * wx1 * vy0 * vx1;
        meta_w[it * 4 + 2] = mv * wy1 * wx0 * vy1 * vx0;
        meta_w[it * 4 + 3] = mv * wy1 * wx1 * vy1 * vx1;
        meta_i[it * 4 + 0] = (y0c * W_ + x0c) << 8;   // pre-scaled row offset (u16 units)
        meta_i[it * 4 + 1] = (y0c * W_ + x1c) << 8;
        meta_i[it * 4 + 2] = (y1c * W_ + x0c) << 8;
        meta_i[it * 4 + 3] = (y1c * W_ + x1c) << 8;
    }
    __syncthreads();

    // ---- prologue: stage step 0 into v[0]; prefetch step 1 gathers into gg[1]
    uint2 gg[2][4]; f32x4 mwr[2];
    issue_gather(xtb + 0 + oct * 4, &meta_w[0], &meta_i[0], gpos, gg[0], mwr[0]);
    interp_store(gg[0], mwr[0], &lds_v[0][gpos * VROW + oct * 4]);
    issue_gather(xtb + 32 + oct * 4, &meta_w[0], &meta_i[0], gpos, gg[1], mwr[1]);  // s=1: k=0,c0=32
    __syncthreads();

    f32x4 acc[2][4];
#pragma unroll
    for (int i = 0; i < 2; ++i)
#pragma unroll
        for (int j = 0; j < 4; ++j) acc[i][j] = (f32x4){0.f, 0.f, 0.f, 0.f};

#pragma unroll 2
    for (int s = 0; s < NSTEP; ++s) {
        const int pa = s & 1;

        // current step's weight frags (L2/L1-resident; issue first for slack)
        short8 bcur[4];
#pragma unroll
        for (int ni = 0; ni < 4; ++ni)
            bcur[ni] = *(const short8*)
                &wimg[(((size_t)s * 16 + wid * 4 + ni) * 64 + lane) * 8];

        // issue gathers for s+2 into the set freed last iteration (distance-2 prefetch)
        if (s + 2 < NSTEP) {
            const int sn = s + 2;
            const int kn = sn >> 3, c0n = (sn & 7) * 32;
            issue_gather(xtb + c0n + oct * 4, &meta_w[kn * 128], &meta_i[kn * 128],
                         gpos, gg[pa], mwr[pa]);
        }

        // A-frags for current step from LDS
        short8 af[2];
#pragma unroll
        for (int mi = 0; mi < 2; ++mi)
            af[mi] = *(const short8*)&lds_v[pa][(mi * 16 + col) * VROW + quad * 8];

        // MFMA
#pragma unroll
        for (int mi = 0; mi < 2; ++mi)
#pragma unroll
            for (int ni = 0; ni < 4; ++ni)
                acc[mi][ni] = __builtin_amdgcn_mfma_f32_16x16x32_bf16(
                    af[mi], bcur[ni], acc[mi][ni], 0, 0, 0);

        // interp step s+1 (gathers issued a full iteration ago) into v[1-pa]
        if (s + 1 < NSTEP)
            interp_store(gg[1 - pa], mwr[1 - pa], &lds_v[1 - pa][gpos * VROW + oct * 4]);

        barrier_lds();   // lgkmcnt-only: global prefetches stay in flight
    }

    // ---- epilogue: store pre-GN output. D: row(pos)=quad*4+r, col(o)=lane&15.
#pragma unroll
    for (int mi = 0; mi < 2; ++mi)
#pragma unroll
        for (int ni = 0; ni < 4; ++ni) {
            const int o  = wid * 64 + ni * 16 + col;
            const int pg = m0 + mi * 16 + quad * 4;
            *(f32x4*)(out + (((size_t)b * O_ + o) << 12) + pg) = acc[mi][ni];
        }

    // ---- GN stats: (wave, ni) = one 16-channel group x 32 positions
#pragma unroll
    for (int ni = 0; ni < 4; ++ni) {
        float s = 0.f, s2 = 0.f;
#pragma unroll
        for (int mi = 0; mi < 2; ++mi) {
            f32x4 v = acc[mi][ni];
            s  += v.x + v.y + v.z + v.w;
            s2 += v.x * v.x + v.y * v.y + v.z * v.z + v.w * v.w;
        }
#pragma unroll
        for (int d = 32; d > 0; d >>= 1) {
            s  += __shfl_xor(s, d, 64);
            s2 += __shfl_xor(s2, d, 64);
        }
        if (lane == 0) {
            const int gI = wid * 4 + ni;
            atomicAdd(&stats[b * GROUPS_ + gI], s);
            atomicAdd(&stats[128 + b * GROUPS_ + gI], s2);
        }
    }
}

// ---------------------------------------------------------------- apply GN in place
__global__ void k_gn(float* __restrict__ out, const float* __restrict__ stats,
                     const float* __restrict__ gamma, const float* __restrict__ beta) {
    const int blk = blockIdx.x;            // b*256 + o
    const int b = blk >> 8, o = blk & 255;
    const int gI = b * GROUPS_ + (o >> 4);
    const float n = 65536.f;               // (C/G)*H*W
    const float mean = stats[gI] / n;
    const float var  = stats[128 + gI] / n - mean * mean;
    const float inv  = rsqrtf(fmaxf(var, 0.f) + EPS_);
    const float scale = inv * gamma[o];
    const float shift = beta[o] - mean * scale;
    f32x4* p = (f32x4*)(out + ((size_t)blk << 12));
    const int t = threadIdx.x;
#pragma unroll
    for (int i = 0; i < 4; ++i) {
        f32x4 v = p[t + i * 256];
        p[t + i * 256] = v * scale + shift;
    }
}

extern "C" void kernel_launch(void* const* d_in, const int* in_sizes, int n_in,
                              void* d_out, int out_size, void* d_ws, size_t ws_size,
                              hipStream_t stream) {
    const float* x     = (const float*)d_in[0];
    const float* offp  = (const float*)d_in[1];
    const float* mskp  = (const float*)d_in[2];
    const float* w     = (const float*)d_in[3];
    const float* gamma = (const float*)d_in[4];
    const float* beta  = (const float*)d_in[5];
    float* outp = (float*)d_out;

    u16*   xt    = (u16*)d_ws;
    u16*   wimg  = (u16*)((char*)d_ws + WIMG_OFF);
    float* stats = (float*)((char*)d_ws + STATS_OFF);

    hipMemsetAsync(stats, 0, 1024, stream);
    k_prep<<<dim3(8192 + 72), dim3(256), 0, stream>>>(x, xt, w, wimg);
    k_dcn<<<dim3(1024), dim3(256), 0, stream>>>(xt, wimg, offp, mskp, outp, stats);
    k_gn<<<dim3(2048), dim3(256), 0, stream>>>(outp, stats, gamma, beta);
}

// Round 5
// 193.776 us; speedup vs baseline: 1.1856x; 1.1856x over previous
//
#include <hip/hip_runtime.h>
#include <stdint.h>

// DyDCNv2 + GroupNorm(16). B=8, C=O=256, H=W=64, fp32 in/out.
// Implicit GEMM M=32768,N=256,K=2304 bf16 MFMA.
// R5: R3 tile shape (64pos x 256n, grid 512, XCD-affine) + register dbuf weight
// prefetch, single-buffer gather prefetch (issue top, interp bottom), lgkm-only
// barriers (global loads survive), truncation bf16 pack in hot interp,
// vectorized k_prep.

#define B_ 8
#define C_ 256
#define O_ 256
#define H_ 64
#define W_ 64
#define HW_ 4096
#define KTOT 2304
#define GROUPS_ 16
#define EPS_ 1e-5f
#define NSTEP 36           // 36 steps x 64 ch
#define VROW 72            // lds_v row stride in u16 (64 data + 8 pad)

typedef float  f32x4  __attribute__((ext_vector_type(4)));
typedef short  short8 __attribute__((ext_vector_type(8)));
typedef unsigned int   u32;
typedef unsigned short u16;

// workspace layout (bytes)
#define XT_BYTES (B_*HW_*C_*2)                 // 16,777,216  xt [B][HW][C] bf16
#define WIMG_OFF  XT_BYTES
#define WIMG_BYTES (72*16*64*16)               // 1,179,648  frag-packed bf16 weights
#define STATS_OFF (WIMG_OFF + WIMG_BYTES)      // 256 floats

__device__ __forceinline__ u32 bf16r(float f) {  // RNE f32->bf16
    u32 u = __float_as_uint(f);
    return (u + 0x7fffu + ((u >> 16) & 1u)) >> 16;
}
__device__ __forceinline__ u32 pack_bf16x2(float lo, float hi) {
    return bf16r(lo) | (bf16r(hi) << 16);
}
// truncation pack (2 ops): round-toward-zero, signed errors cancel over K=2304
__device__ __forceinline__ u32 pack_trunc(float lo, float hi) {
    return (__float_as_uint(hi) & 0xffff0000u) | (__float_as_uint(lo) >> 16);
}
__device__ __forceinline__ float bflo(u32 u) { return __uint_as_float(u << 16); }
__device__ __forceinline__ float bfhi(u32 u) { return __uint_as_float(u & 0xffff0000u); }

// barrier waiting only on LDS ops: register-destined global loads stay in flight
__device__ __forceinline__ void barrier_lds() {
    asm volatile("s_waitcnt lgkmcnt(0)\n\ts_barrier" ::: "memory");
}

// ---------------------------------------------------------------- prep: transpose + packw
__global__ void k_prep(const float* __restrict__ x, u16* __restrict__ xt,
                       const float* __restrict__ w, u16* __restrict__ wimg) {
    const int bid = blockIdx.x;
    const int tid = threadIdx.x;
    if (bid < 2048) {
        // transpose x[B][C][HW] -> xt[B][HW][C] bf16, 64c x 64p tiles
        __shared__ float tile[64][65];
        const int b = bid >> 8, ct = (bid >> 6) & 3, pt = bid & 63;
#pragma unroll
        for (int pass = 0; pass < 4; ++pass) {
            const int r  = (tid >> 4) + pass * 16;
            const int pq = tid & 15;
            const f32x4 v = *(const f32x4*)&x[(((size_t)(b * C_ + ct * 64 + r)) << 12)
                                              + pt * 64 + pq * 4];
            tile[r][pq * 4 + 0] = v.x;
            tile[r][pq * 4 + 1] = v.y;
            tile[r][pq * 4 + 2] = v.z;
            tile[r][pq * 4 + 3] = v.w;
        }
        __syncthreads();
        const int pr = tid >> 2, cg = tid & 3;    // 64 p-rows x 4 groups of 16 ch
        u32 o[8];
#pragma unroll
        for (int j = 0; j < 8; ++j)
            o[j] = pack_bf16x2(tile[cg * 16 + 2 * j][pr], tile[cg * 16 + 2 * j + 1][pr]);
        u16* dst = &xt[(((size_t)b << 12) + pt * 64 + pr) * 256 + ct * 64 + cg * 16];
        *(uint4*)dst       = *(uint4*)&o[0];
        *(uint4*)(dst + 8) = *(uint4*)&o[4];
    } else {
        // pack weights: wimg[sub][frag][lane][8], sub = k*8+ctile;
        // lane(col,quad) holds W[n=frag*16+col][c0+quad*8+j][k]
        const int sub = bid - 2048;       // 0..71
        const int k  = sub >> 3;
        const int c0 = (sub & 7) * 32;
#pragma unroll
        for (int i = 0; i < 4; ++i) {
            const int item = tid + i * 256;    // frag*64 + lane
            const int lane = item & 63;
            const int frag = item >> 6;
            const int col = lane & 15, quad = lane >> 4;
            const int n = frag * 16 + col;
            const float* src = w + (size_t)n * KTOT + (size_t)(c0 + quad * 8) * 9 + k;
            u32 o[4];
#pragma unroll
            for (int j = 0; j < 4; ++j)
                o[j] = pack_bf16x2(src[(size_t)(2 * j) * 9], src[(size_t)(2 * j + 1) * 9]);
            *(uint4*)&wimg[((size_t)sub * 1024 + item) * 8] = *(uint4*)o;
        }
    }
}

// ---------------------------------------------------------------- k_dcn helpers
// gather 16 ch (2 x uint4) per corner; meta_i holds pre-scaled row offsets (row*256)
__device__ __forceinline__ void issue_gather(const u16* __restrict__ cb,
                                             const float* __restrict__ mwp,
                                             const int* __restrict__ mip,
                                             int gpos, uint4 g[8], f32x4& mw) {
    mw = *(const f32x4*)&mwp[gpos * 4];
    const int4 ix = *(const int4*)&mip[gpos * 4];
    const u16* p0 = cb + ix.x;
    const u16* p1 = cb + ix.y;
    const u16* p2 = cb + ix.z;
    const u16* p3 = cb + ix.w;
    g[0] = *(const uint4*)p0; g[1] = *(const uint4*)(p0 + 8);
    g[2] = *(const uint4*)p1; g[3] = *(const uint4*)(p1 + 8);
    g[4] = *(const uint4*)p2; g[5] = *(const uint4*)(p2 + 8);
    g[6] = *(const uint4*)p3; g[7] = *(const uint4*)(p3 + 8);
}

__device__ __forceinline__ void interp_store(const uint4 g[8], f32x4 mw, u16* dst) {
    float s[16];
#pragma unroll
    for (int i = 0; i < 16; ++i) s[i] = 0.f;
    const float ww[4] = {mw.x, mw.y, mw.z, mw.w};
#pragma unroll
    for (int cr = 0; cr < 4; ++cr) {
        const float wg = ww[cr];
        const uint4 a = g[2 * cr], bq = g[2 * cr + 1];
        s[0]  += wg * bflo(a.x);  s[1]  += wg * bfhi(a.x);
        s[2]  += wg * bflo(a.y);  s[3]  += wg * bfhi(a.y);
        s[4]  += wg * bflo(a.z);  s[5]  += wg * bfhi(a.z);
        s[6]  += wg * bflo(a.w);  s[7]  += wg * bfhi(a.w);
        s[8]  += wg * bflo(bq.x); s[9]  += wg * bfhi(bq.x);
        s[10] += wg * bflo(bq.y); s[11] += wg * bfhi(bq.y);
        s[12] += wg * bflo(bq.z); s[13] += wg * bfhi(bq.z);
        s[14] += wg * bflo(bq.w); s[15] += wg * bfhi(bq.w);
    }
    uint4 pk0, pk1;
    pk0.x = pack_trunc(s[0], s[1]);   pk0.y = pack_trunc(s[2], s[3]);
    pk0.z = pack_trunc(s[4], s[5]);   pk0.w = pack_trunc(s[6], s[7]);
    pk1.x = pack_trunc(s[8], s[9]);   pk1.y = pack_trunc(s[10], s[11]);
    pk1.z = pack_trunc(s[12], s[13]); pk1.w = pack_trunc(s[14], s[15]);
    *(uint4*)dst = pk0;
    *(uint4*)(dst + 8) = pk1;
}

__device__ __forceinline__ void load_wfrags(const u16* __restrict__ wimg, int s,
                                            int wid, int lane, short8 bf[8]) {
#pragma unroll
    for (int kc = 0; kc < 2; ++kc)
#pragma unroll
        for (int ni = 0; ni < 4; ++ni)
            bf[kc * 4 + ni] = *(const short8*)
                &wimg[(((size_t)(2 * s + kc) * 16 + wid * 4 + ni) * 64 + lane) * 8];
}

// ---------------------------------------------------------------- main fused DCN GEMM
// grid 512: b = gid%8 (XCD-affine), m-tile 64 pos. 256 thr = 4 waves;
// wave w: 64 pos x n in [w*64, +64). Step = 64 channels (2 MFMA sub-steps).
__launch_bounds__(256, 2)
__global__ void k_dcn(const u16* __restrict__ xt, const u16* __restrict__ wimg,
                      const float* __restrict__ offp, const float* __restrict__ mskp,
                      float* __restrict__ out, float* __restrict__ stats) {
    __shared__ __align__(16) float meta_w[9 * 64 * 4];   // 9216 B
    __shared__ __align__(16) int   meta_i[9 * 64 * 4];   // 9216 B
    __shared__ __align__(16) u16   lds_v[2][64 * VROW];  // 18432 B dbuf val tile

    const int tid = threadIdx.x;
    const int gid = blockIdx.x;
    const int b   = gid & 7;            // XCD-affine
    const int m0  = (gid >> 3) * 64;
    const int lane = tid & 63, wid = tid >> 6;
    const int col = lane & 15, quad = lane >> 4;
    const int gpos = tid >> 2, oct = tid & 3;   // gather role: (pos 0..63, 16-ch oct)

    const u16* xtb = xt + ((size_t)b << 20);

    // ---- bilinear meta for 64 positions x 9 kernel points, once
    for (int it = tid; it < 576; it += 256) {
        const int pos = it & 63, k = it >> 6;
        const int pg = m0 + pos;
        const int hh = pg >> 6, wwi = pg & 63;
        const float dy = offp[((size_t)(b * 18 + 2 * k) << 12) + pg];
        const float dx = offp[((size_t)(b * 18 + 2 * k + 1) << 12) + pg];
        const float mv = mskp[((size_t)(b * 9 + k) << 12) + pg];
        const float ys = (float)(hh + (k / 3) - 1) + dy;
        const float xs = (float)(wwi + (k % 3) - 1) + dx;
        const float y0f = floorf(ys), x0f = floorf(xs);
        const int y0 = (int)y0f, x0 = (int)x0f;
        const float wy1 = ys - y0f, wx1 = xs - x0f;
        const float wy0 = 1.f - wy1, wx0 = 1.f - wx1;
        const int y1 = y0 + 1, x1 = x0 + 1;
        const float vy0 = (y0 >= 0 && y0 < H_) ? 1.f : 0.f;
        const float vy1 = (y1 >= 0 && y1 < H_) ? 1.f : 0.f;
        const float vx0 = (x0 >= 0 && x0 < W_) ? 1.f : 0.f;
        const float vx1 = (x1 >= 0 && x1 < W_) ? 1.f : 0.f;
        const int y0c = min(max(y0, 0), H_ - 1), y1c = min(max(y1, 0), H_ - 1);
        const int x0c = min(max(x0, 0), W_ - 1), x1c = min(max(x1, 0), W_ - 1);
        meta_w[it * 4 + 0] = mv * wy0 * wx0 * vy0 * vx0;
        meta_w[it * 4 + 1] = mv * wy0 * wx1 * vy0 * vx1;
        meta_w[it * 4 + 2] = mv * wy1 * wx0 * vy1 * vx0;
        meta_w[it * 4 + 3] = mv * wy1 * wx1 * vy1 * vx1;
        meta_i[it * 4 + 0] = (y0c * W_ + x0c) << 8;   // row offsets in u16 units
        meta_i[it * 4 + 1] = (y0c * W_ + x1c) << 8;
        meta_i[it * 4 + 2] = (y1c * W_ + x0c) << 8;
        meta_i[it * 4 + 3] = (y1c * W_ + x1c) << 8;
    }
    __syncthreads();

    // ---- prologue: stage step 0 into lds_v[0]; load weight frags for step 0
    uint4 g[8]; f32x4 mw; short8 bf_cur[8], bf_nxt[8];
    issue_gather(xtb + 0 + oct * 16, &meta_w[0], &meta_i[0], gpos, g, mw);
    load_wfrags(wimg, 0, wid, lane, bf_cur);
    interp_store(g, mw, &lds_v[0][gpos * VROW + oct * 16]);
    __syncthreads();

    f32x4 acc[4][4];
#pragma unroll
    for (int i = 0; i < 4; ++i)
#pragma unroll
        for (int j = 0; j < 4; ++j) acc[i][j] = (f32x4){0.f, 0.f, 0.f, 0.f};

#pragma unroll 2
    for (int s = 0; s < NSTEP; ++s) {
        const int p = s & 1;
        const bool pf = (s + 1 < NSTEP);

        // 1. weight frags for s+1 (distance-1 register prefetch)
        if (pf) load_wfrags(wimg, s + 1, wid, lane, bf_nxt);

        // 2. gathers for s+1 (consumed at bottom of this step, ~full-MFMA slack)
        if (pf) {
            const int sn = s + 1;
            const int kn = sn >> 2, c0n = (sn & 3) * 64;
            issue_gather(xtb + c0n + oct * 16, &meta_w[kn * 256], &meta_i[kn * 256],
                         gpos, g, mw);
        }

        // 3. compute current step: 2 sub-steps of 32 ch
#pragma unroll
        for (int kc = 0; kc < 2; ++kc) {
            short8 af[4];
#pragma unroll
            for (int mi = 0; mi < 4; ++mi)
                af[mi] = *(const short8*)
                    &lds_v[p][(mi * 16 + col) * VROW + kc * 32 + quad * 8];
#pragma unroll
            for (int mi = 0; mi < 4; ++mi)
#pragma unroll
                for (int ni = 0; ni < 4; ++ni)
                    acc[mi][ni] = __builtin_amdgcn_mfma_f32_16x16x32_bf16(
                        af[mi], bf_cur[kc * 4 + ni], acc[mi][ni], 0, 0, 0);
        }

        // 4. interp s+1 into the other buffer
        if (pf) interp_store(g, mw, &lds_v[1 - p][gpos * VROW + oct * 16]);

        // 5. LDS-only barrier: weight/gather prefetches stay in flight
        barrier_lds();

#pragma unroll
        for (int i = 0; i < 8; ++i) bf_cur[i] = bf_nxt[i];
    }

    // ---- epilogue: store pre-GN output. D: row(pos)=quad*4+r, col(o)=lane&15.
#pragma unroll
    for (int mi = 0; mi < 4; ++mi)
#pragma unroll
        for (int ni = 0; ni < 4; ++ni) {
            const int o  = wid * 64 + ni * 16 + col;
            const int pg = m0 + mi * 16 + quad * 4;
            *(f32x4*)(out + (((size_t)b * O_ + o) << 12) + pg) = acc[mi][ni];
        }

    // ---- GN stats: (wave, ni) = one 16-channel group x 64 positions
#pragma unroll
    for (int ni = 0; ni < 4; ++ni) {
        float s = 0.f, s2 = 0.f;
#pragma unroll
        for (int mi = 0; mi < 4; ++mi) {
            f32x4 v = acc[mi][ni];
            s  += v.x + v.y + v.z + v.w;
            s2 += v.x * v.x + v.y * v.y + v.z * v.z + v.w * v.w;
        }
#pragma unroll
        for (int d = 32; d > 0; d >>= 1) {
            s  += __shfl_xor(s, d, 64);
            s2 += __shfl_xor(s2, d, 64);
        }
        if (lane == 0) {
            const int gI = wid * 4 + ni;
            atomicAdd(&stats[b * GROUPS_ + gI], s);
            atomicAdd(&stats[128 + b * GROUPS_ + gI], s2);
        }
    }
}

// ---------------------------------------------------------------- apply GN in place
__global__ void k_gn(float* __restrict__ out, const float* __restrict__ stats,
                     const float* __restrict__ gamma, const float* __restrict__ beta) {
    const int blk = blockIdx.x;            // b*256 + o
    const int b = blk >> 8, o = blk & 255;
    const int gI = b * GROUPS_ + (o >> 4);
    const float n = 65536.f;               // (C/G)*H*W
    const float mean = stats[gI] / n;
    const float var  = stats[128 + gI] / n - mean * mean;
    const float inv  = rsqrtf(fmaxf(var, 0.f) + EPS_);
    const float scale = inv * gamma[o];
    const float shift = beta[o] - mean * scale;
    f32x4* p = (f32x4*)(out + ((size_t)blk << 12));
    const int t = threadIdx.x;
#pragma unroll
    for (int i = 0; i < 4; ++i) {
        f32x4 v = p[t + i * 256];
        p[t + i * 256] = v * scale + shift;
    }
}

extern "C" void kernel_launch(void* const* d_in, const int* in_sizes, int n_in,
                              void* d_out, int out_size, void* d_ws, size_t ws_size,
                              hipStream_t stream) {
    const float* x     = (const float*)d_in[0];
    const float* offp  = (const float*)d_in[1];
    const float* mskp  = (const float*)d_in[2];
    const float* w     = (const float*)d_in[3];
    const float* gamma = (const float*)d_in[4];
    const float* beta  = (const float*)d_in[5];
    float* outp = (float*)d_out;

    u16*   xt    = (u16*)d_ws;
    u16*   wimg  = (u16*)((char*)d_ws + WIMG_OFF);
    float* stats = (float*)((char*)d_ws + STATS_OFF);

    hipMemsetAsync(stats, 0, 1024, stream);
    k_prep<<<dim3(2048 + 72), dim3(256), 0, stream>>>(x, xt, w, wimg);
    k_dcn<<<dim3(512), dim3(256), 0, stream>>>(xt, wimg, offp, mskp, outp, stats);
    k_gn<<<dim3(2048), dim3(256), 0, stream>>>(outp, stats, gamma, beta);
}